// Round 1
// baseline (64.160 us; speedup 1.0000x reference)
//
#include <hip/hip_runtime.h>
#include <math.h>

#define TSAVE    128
#define MAXSTEPS 256

#define CF(x) ((float)(x))

__device__ __forceinline__ float bcastf(float v, int lane) {
  return __int_as_float(__builtin_amdgcn_readlane(__float_as_int(v), lane));
}

// jax.nn.softplus(x) = logaddexp(x, 0) = max(x,0) + log1p(exp(-|x|))
__device__ __forceinline__ float softplus_f(float x) {
  return fmaxf(x, 0.0f) + log1pf(expf(-fabsf(x)));
}

// matvec: result[lane] = sum_j Wr[j] * u[j] + bias ; u[j] broadcast via readlane
#define MATVEC(Wr, uin, bias, result) do {                                  \
  float _a0 = 0.f, _a1 = 0.f, _a2 = 0.f, _a3 = 0.f;                         \
  _Pragma("unroll")                                                         \
  for (int _j = 0; _j < 64; _j += 4) {                                      \
    _a0 = fmaf(bcastf(uin, _j+0), Wr[_j+0], _a0);                           \
    _a1 = fmaf(bcastf(uin, _j+1), Wr[_j+1], _a1);                           \
    _a2 = fmaf(bcastf(uin, _j+2), Wr[_j+2], _a2);                           \
    _a3 = fmaf(bcastf(uin, _j+3), Wr[_j+3], _a3);                           \
  }                                                                         \
  result = ((_a0 + _a1) + (_a2 + _a3)) + bias;                              \
} while (0)

#define VFEVAL(uin, fout) do {                                              \
  float _h1, _h2, _pz;                                                      \
  MATVEC(W1r, uin, b1v, _pz); _h1 = softplus_f(_pz);                        \
  MATVEC(W2r, _h1, b2v, _pz); _h2 = softplus_f(_pz);                        \
  MATVEC(W3r, _h2, b3v, fout);                                              \
} while (0)

extern "C" __global__ void __launch_bounds__(64, 1)
ode_tsit5_kernel(const float* __restrict__ ts,
                 const float* __restrict__ y0,
                 const float* __restrict__ w1, const float* __restrict__ b1,
                 const float* __restrict__ w2, const float* __restrict__ b2,
                 const float* __restrict__ w3, const float* __restrict__ b3,
                 float* __restrict__ out)
{
  const int lane = threadIdx.x;
  const int b    = blockIdx.x;

  __shared__ float ts_s[TSAVE];
  ts_s[lane]      = ts[lane];
  ts_s[lane + 64] = ts[lane + 64];
  __syncthreads();

  // lane i holds row i of each weight matrix (h[i] = sum_j u[j]*W[i][j])
  float W1r[64], W2r[64], W3r[64];
  {
    const float4* r1 = (const float4*)(w1 + lane * 64);
    const float4* r2 = (const float4*)(w2 + lane * 64);
    const float4* r3 = (const float4*)(w3 + lane * 64);
#pragma unroll
    for (int j4 = 0; j4 < 16; ++j4) {
      float4 v1 = r1[j4];
      W1r[4*j4+0]=v1.x; W1r[4*j4+1]=v1.y; W1r[4*j4+2]=v1.z; W1r[4*j4+3]=v1.w;
      float4 v2 = r2[j4];
      W2r[4*j4+0]=v2.x; W2r[4*j4+1]=v2.y; W2r[4*j4+2]=v2.z; W2r[4*j4+3]=v2.w;
      float4 v3 = r3[j4];
      W3r[4*j4+0]=v3.x; W3r[4*j4+1]=v3.y; W3r[4*j4+2]=v3.z; W3r[4*j4+3]=v3.w;
    }
  }
  const float b1v = b1[lane], b2v = b2[lane], b3v = b3[lane];

  float y = y0[(size_t)b * 64 + lane];
  const float t0v = ts_s[0], t1v = ts_s[TSAVE - 1];
  float t = t0v;
  float h = ts_s[1] - ts_s[0];
  float f;
  VFEVAL(y, f);   // f0 = vf(y0)  (FSAL k1)

  float* outb = out + (size_t)b * TSAVE * 64;
  outb[lane] = y;     // ts[0] == t0 -> theta = 0 -> y0
  int p = 1;

  bool donebrk = false;
  float seg_tl = t, seg_tr = t, seg_yl = y, seg_yr = y;

  for (int it = 0; it < MAXSTEPS; ++it) {
    if ((t1v - t) <= 1e-10f * (t1v - t0v)) { donebrk = true; break; }
    const float heff = fminf(h, t1v - t);
    const float k1 = f;
    float u, k2, k3, k4, k5, k6, k7, ynew;

    u = y + heff * (CF(0.161) * k1);
    VFEVAL(u, k2);
    u = y + heff * (CF(-0.008480655492356989) * k1 + CF(0.335480655492357) * k2);
    VFEVAL(u, k3);
    u = y + heff * (CF(2.8971530571054935) * k1 + CF(-6.359448489975075) * k2
                  + CF(4.3622954328695815) * k3);
    VFEVAL(u, k4);
    u = y + heff * (CF(5.325864828439257) * k1 + CF(-11.748883564062828) * k2
                  + CF(7.4955393428898365) * k3 + CF(-0.09249506636175525) * k4);
    VFEVAL(u, k5);
    u = y + heff * (CF(5.86145544294642) * k1 + CF(-12.92096931784711) * k2
                  + CF(8.159367898576159) * k3 + CF(-0.071584973281401) * k4
                  + CF(-0.028269050394068383) * k5);
    VFEVAL(u, k6);
    ynew = y + heff * (CF(0.09646076681806523) * k1 + CF(0.01) * k2
                     + CF(0.4798896504144996) * k3 + CF(1.379008574103742) * k4
                     + CF(-3.290069515436081) * k5 + CF(2.324710524099774) * k6);
    VFEVAL(ynew, k7);

    const float err = heff * (CF(-0.00178001105222577714) * k1
                            + CF(-0.0008164344596567469) * k2
                            + CF(0.007880878010261995)  * k3
                            + CF(-0.1447110071732629)   * k4
                            + CF(0.5823571654525552)    * k5
                            + CF(-0.45808210592918697)  * k6
                            + CF(0.015151515151515152)  * k7);
    const float scale = 1e-6f + 1e-3f * fmaxf(fabsf(y), fabsf(ynew));
    const float r = err / scale;
    float ss = r * r;
#pragma unroll
    for (int m = 1; m < 64; m <<= 1) ss += __shfl_xor(ss, m, 64);
    const float errn = sqrtf(ss * (1.0f / 64.0f));
    const bool accept = errn <= 1.0f;
    float factor = 0.9f * powf(errn + 1e-10f, -0.2f);
    factor = fminf(fmaxf(factor, 0.2f), 5.0f);

    if (accept) {
      const float tnew = t + heff;
      // emit all save points in (t, tnew]; searchsorted 'left' picks the
      // first step index whose t reaches >= s, which is exactly this step.
      while (p < TSAVE) {
        const float s = ts_s[p];
        if (!(s <= tnew)) break;
        const float theta = (s - t) / (tnew - t);
        outb[(size_t)p * 64 + lane] = y + theta * (ynew - y);
        ++p;
      }
      seg_tl = t; seg_tr = tnew; seg_yl = y; seg_yr = ynew;
      t = tnew; y = ynew; f = k7;
    } else {
      seg_tl = t; seg_tr = t; seg_yl = y; seg_yr = y;
    }
    h = heff * factor;
  }

  // tail: save points never reached during stepping
  if (p < TSAVE) {
    const float denom = seg_tr - seg_tl;
    if (!donebrk && denom > 0.f) {
      // ran out of steps, last real step accepted -> clipped searchsorted
      // brackets with the final segment => linear extrapolation (theta > 1)
      for (; p < TSAVE; ++p) {
        const float s = ts_s[p];
        const float theta = (s - seg_tl) / denom;
        outb[(size_t)p * 64 + lane] = seg_yl + theta * (seg_yr - seg_yl);
      }
    } else {
      // frozen steps repeat (t,y): denom==0 -> theta=0 -> current y
      for (; p < TSAVE; ++p) outb[(size_t)p * 64 + lane] = y;
    }
  }
}

extern "C" void kernel_launch(void* const* d_in, const int* in_sizes, int n_in,
                              void* d_out, int out_size, void* d_ws, size_t ws_size,
                              hipStream_t stream) {
  const float* ts = (const float*)d_in[0];
  const float* y0 = (const float*)d_in[1];
  const float* w1 = (const float*)d_in[2];
  const float* b1 = (const float*)d_in[3];
  const float* w2 = (const float*)d_in[4];
  const float* b2 = (const float*)d_in[5];
  const float* w3 = (const float*)d_in[6];
  const float* b3 = (const float*)d_in[7];
  float* out = (float*)d_out;
  const int B = in_sizes[1] / 64;
  hipLaunchKernelGGL(ode_tsit5_kernel, dim3(B), dim3(64), 0, stream,
                     ts, y0, w1, b1, w2, b2, w3, b3, out);
}

// Round 2
// 49.116 us; speedup vs baseline: 1.3063x; 1.3063x over previous
//
#include <hip/hip_runtime.h>
#include <math.h>

#define TSAVE    128
#define MAXSTEPS 256

#define CF(x) ((float)(x))

typedef float v2f __attribute__((ext_vector_type(2)));

__device__ __forceinline__ float bcastf(float v, int lane) {
  return __int_as_float(__builtin_amdgcn_readlane(__float_as_int(v), lane));
}

// packed fp32 FMA: acc = w * u + acc (2 lanes of f32 per instruction).
// u is wave-uniform (built from readlanes) -> lands in an SGPR pair (VOP3P
// allows one scalar source operand).
__device__ __forceinline__ void pk_fma(v2f& acc, v2f w, v2f u) {
  asm("v_pk_fma_f32 %0, %1, %2, %0" : "+v"(acc) : "v"(w), "s"(u));
}

// jax.nn.softplus(x) = max(x,0) + log1p(exp(-|x|)); z=exp(-|x|) in (0,1] so
// plain log(1+z) via fast hw log/exp is accurate to ~1e-7 abs.
__device__ __forceinline__ float softplus_f(float x) {
  return fmaxf(x, 0.0f) + __logf(1.0f + __expf(-fabsf(x)));
}

// matvec: result[lane] = sum_j Wp[j/2][j%2] * u[j] + bias
// 64 readlane broadcasts + 32 v_pk_fma_f32, 8 independent chains (4 packed).
#define MATVEC(Wp, uin, bias, result) do {                                  \
  v2f _a0 = {0.f,0.f}, _a1 = {0.f,0.f}, _a2 = {0.f,0.f}, _a3 = {0.f,0.f};   \
  _Pragma("unroll")                                                         \
  for (int _j = 0; _j < 64; _j += 8) {                                      \
    v2f _u0 = { bcastf(uin, _j+0), bcastf(uin, _j+1) };                     \
    v2f _u1 = { bcastf(uin, _j+2), bcastf(uin, _j+3) };                     \
    v2f _u2 = { bcastf(uin, _j+4), bcastf(uin, _j+5) };                     \
    v2f _u3 = { bcastf(uin, _j+6), bcastf(uin, _j+7) };                     \
    pk_fma(_a0, Wp[_j/2+0], _u0);                                           \
    pk_fma(_a1, Wp[_j/2+1], _u1);                                           \
    pk_fma(_a2, Wp[_j/2+2], _u2);                                           \
    pk_fma(_a3, Wp[_j/2+3], _u3);                                           \
  }                                                                         \
  v2f _s = (_a0 + _a1) + (_a2 + _a3);                                       \
  result = (_s.x + _s.y) + bias;                                            \
} while (0)

#define VFEVAL(uin, fout) do {                                              \
  float _h1, _h2, _pz;                                                      \
  MATVEC(W1p, uin, b1v, _pz); _h1 = softplus_f(_pz);                        \
  MATVEC(W2p, _h1, b2v, _pz); _h2 = softplus_f(_pz);                        \
  MATVEC(W3p, _h2, b3v, fout);                                              \
} while (0)

extern "C" __global__ void __launch_bounds__(64, 1)
ode_tsit5_kernel(const float* __restrict__ ts,
                 const float* __restrict__ y0,
                 const float* __restrict__ w1, const float* __restrict__ b1,
                 const float* __restrict__ w2, const float* __restrict__ b2,
                 const float* __restrict__ w3, const float* __restrict__ b3,
                 float* __restrict__ out)
{
  const int lane = threadIdx.x;
  const int b    = blockIdx.x;

  __shared__ float ts_s[TSAVE];
  ts_s[lane]      = ts[lane];
  ts_s[lane + 64] = ts[lane + 64];
  __syncthreads();

  // lane i holds row i of each weight matrix, as 32 packed f32 pairs
  v2f W1p[32], W2p[32], W3p[32];
  {
    const float4* r1 = (const float4*)(w1 + lane * 64);
    const float4* r2 = (const float4*)(w2 + lane * 64);
    const float4* r3 = (const float4*)(w3 + lane * 64);
#pragma unroll
    for (int j4 = 0; j4 < 16; ++j4) {
      float4 v1 = r1[j4];
      W1p[2*j4+0] = (v2f){v1.x, v1.y}; W1p[2*j4+1] = (v2f){v1.z, v1.w};
      float4 v2 = r2[j4];
      W2p[2*j4+0] = (v2f){v2.x, v2.y}; W2p[2*j4+1] = (v2f){v2.z, v2.w};
      float4 v3 = r3[j4];
      W3p[2*j4+0] = (v2f){v3.x, v3.y}; W3p[2*j4+1] = (v2f){v3.z, v3.w};
    }
  }
  const float b1v = b1[lane], b2v = b2[lane], b3v = b3[lane];

  float y = y0[(size_t)b * 64 + lane];
  const float t0v = ts_s[0], t1v = ts_s[TSAVE - 1];
  float t = t0v;
  float h = ts_s[1] - ts_s[0];
  float f;
  VFEVAL(y, f);   // f0 = vf(y0)  (FSAL k1)

  float* outb = out + (size_t)b * TSAVE * 64;
  outb[lane] = y;     // ts[0] == t0 -> theta = 0 -> y0
  int p = 1;

  bool donebrk = false;
  float seg_tl = t, seg_tr = t, seg_yl = y, seg_yr = y;

  for (int it = 0; it < MAXSTEPS; ++it) {
    if ((t1v - t) <= 1e-10f * (t1v - t0v)) { donebrk = true; break; }
    const float heff = fminf(h, t1v - t);
    const float k1 = f;
    float u, k2, k3, k4, k5, k6, k7, ynew;

    u = y + heff * (CF(0.161) * k1);
    VFEVAL(u, k2);
    u = y + heff * (CF(-0.008480655492356989) * k1 + CF(0.335480655492357) * k2);
    VFEVAL(u, k3);
    u = y + heff * (CF(2.8971530571054935) * k1 + CF(-6.359448489975075) * k2
                  + CF(4.3622954328695815) * k3);
    VFEVAL(u, k4);
    u = y + heff * (CF(5.325864828439257) * k1 + CF(-11.748883564062828) * k2
                  + CF(7.4955393428898365) * k3 + CF(-0.09249506636175525) * k4);
    VFEVAL(u, k5);
    u = y + heff * (CF(5.86145544294642) * k1 + CF(-12.92096931784711) * k2
                  + CF(8.159367898576159) * k3 + CF(-0.071584973281401) * k4
                  + CF(-0.028269050394068383) * k5);
    VFEVAL(u, k6);
    ynew = y + heff * (CF(0.09646076681806523) * k1 + CF(0.01) * k2
                     + CF(0.4798896504144996) * k3 + CF(1.379008574103742) * k4
                     + CF(-3.290069515436081) * k5 + CF(2.324710524099774) * k6);
    VFEVAL(ynew, k7);

    const float err = heff * (CF(-0.00178001105222577714) * k1
                            + CF(-0.0008164344596567469) * k2
                            + CF(0.007880878010261995)  * k3
                            + CF(-0.1447110071732629)   * k4
                            + CF(0.5823571654525552)    * k5
                            + CF(-0.45808210592918697)  * k6
                            + CF(0.015151515151515152)  * k7);
    const float scale = 1e-6f + 1e-3f * fmaxf(fabsf(y), fabsf(ynew));
    const float r = err / scale;
    float ss = r * r;
#pragma unroll
    for (int m = 1; m < 64; m <<= 1) ss += __shfl_xor(ss, m, 64);
    const float errn = sqrtf(ss * (1.0f / 64.0f));
    const bool accept = errn <= 1.0f;
    // 0.9 * (errn+1e-10)^-0.2 ; errn >= 0 so exp/log form is exact enough
    float factor = 0.9f * __expf(-0.2f * __logf(errn + 1e-10f));
    factor = fminf(fmaxf(factor, 0.2f), 5.0f);

    if (accept) {
      const float tnew = t + heff;
      // emit all save points in (t, tnew]  (== searchsorted 'left' bracket)
      while (p < TSAVE) {
        const float s = ts_s[p];
        if (!(s <= tnew)) break;
        const float theta = (s - t) / (tnew - t);
        outb[(size_t)p * 64 + lane] = y + theta * (ynew - y);
        ++p;
      }
      seg_tl = t; seg_tr = tnew; seg_yl = y; seg_yr = ynew;
      t = tnew; y = ynew; f = k7;
    } else {
      seg_tl = t; seg_tr = t; seg_yl = y; seg_yr = y;
    }
    h = heff * factor;
  }

  // tail: save points never reached during stepping
  if (p < TSAVE) {
    const float denom = seg_tr - seg_tl;
    if (!donebrk && denom > 0.f) {
      // steps exhausted, last real step accepted -> clipped searchsorted
      // brackets with the final segment => linear extrapolation (theta > 1)
      for (; p < TSAVE; ++p) {
        const float s = ts_s[p];
        const float theta = (s - seg_tl) / denom;
        outb[(size_t)p * 64 + lane] = seg_yl + theta * (seg_yr - seg_yl);
      }
    } else {
      // frozen steps repeat (t,y): denom==0 -> theta=0 -> current y
      for (; p < TSAVE; ++p) outb[(size_t)p * 64 + lane] = y;
    }
  }
}

extern "C" void kernel_launch(void* const* d_in, const int* in_sizes, int n_in,
                              void* d_out, int out_size, void* d_ws, size_t ws_size,
                              hipStream_t stream) {
  const float* ts = (const float*)d_in[0];
  const float* y0 = (const float*)d_in[1];
  const float* w1 = (const float*)d_in[2];
  const float* b1 = (const float*)d_in[3];
  const float* w2 = (const float*)d_in[4];
  const float* b2 = (const float*)d_in[5];
  const float* w3 = (const float*)d_in[6];
  const float* b3 = (const float*)d_in[7];
  float* out = (float*)d_out;
  const int B = in_sizes[1] / 64;
  hipLaunchKernelGGL(ode_tsit5_kernel, dim3(B), dim3(64), 0, stream,
                     ts, y0, w1, b1, w2, b2, w3, b3, out);
}